// Round 15
// baseline (546.083 us; speedup 1.0000x reference)
//
#include <hip/hip_runtime.h>
#include <math.h>

#define B_   16
#define NN   1024
#define DIM_ 512
#define D1_  1536
#define GLU_ 1024

typedef unsigned short u16;
typedef __attribute__((ext_vector_type(8))) short bf16x8;
typedef __attribute__((ext_vector_type(4))) float f32x4;

__device__ __forceinline__ float silu_f(float x) {
    return x / (1.0f + __expf(-x));
}
__device__ __forceinline__ u16 f2b(float f) {           // RNE fp32 -> bf16
    unsigned u = __float_as_uint(f);
    return (u16)((u + 0x7FFF + ((u >> 16) & 1)) >> 16);
}
__device__ __forceinline__ float b2f(u16 s) {
    return __uint_as_float(((unsigned)s) << 16);
}

// ---------------- K0: fused prep (cvt + all transposes + bias concat + RPE hidden MLP) ----------
__launch_bounds__(256)
__global__ void prep_kernel(const float* __restrict__ x, u16* __restrict__ xb,
                            const float* __restrict__ u_w, u16* __restrict__ uwT,
                            const float* __restrict__ v_w, u16* __restrict__ vwT,
                            const float* __restrict__ o_w, u16* __restrict__ owT,
                            const float* __restrict__ l1_w, const float* __restrict__ l2_w,
                            u16* __restrict__ gluT,
                            const float* __restrict__ l3_w, u16* __restrict__ l3T,
                            const float* __restrict__ rpe_ow, u16* __restrict__ owT2,
                            const float* __restrict__ l1_b, const float* __restrict__ l2_b,
                            float* __restrict__ gluB,
                            const float* __restrict__ pos_w, const float* __restrict__ pos_b,
                            const float* __restrict__ lw, const float* __restrict__ lb,
                            u16* __restrict__ y) {
    __shared__ __align__(16) char smem_raw[4352];
    int bb = blockIdx.x;
    int t = threadIdx.x;
    if (bb < 2048) {
        #pragma unroll
        for (int j = 0; j < 4; ++j) {
            int i = bb * 1024 + j * 256 + t;
            float4 f = reinterpret_cast<const float4*>(x)[i];
            unsigned lo = (unsigned)f2b(f.x) | ((unsigned)f2b(f.y) << 16);
            unsigned hi = (unsigned)f2b(f.z) | ((unsigned)f2b(f.w) << 16);
            reinterpret_cast<uint2*>(xb)[i] = make_uint2(lo, hi);
        }
    } else if (bb < 5984) {
        const float* in; u16* out; int K, N, tile;
        if (bb < 2816)      { in = u_w;  out = uwT;  K = 512;  N = 1536; tile = bb - 2048; }
        else if (bb < 3584) { in = v_w;  out = vwT;  K = 512;  N = 1536; tile = bb - 2816; }
        else if (bb < 4352) { in = o_w;  out = owT;  K = 1536; N = 512;  tile = bb - 3584; }
        else if (bb < 4864) { in = l1_w; out = gluT; K = 512;  N = 1024; tile = bb - 4352; }
        else if (bb < 5376) { in = l2_w; out = gluT + (size_t)GLU_ * DIM_; K = 512; N = 1024; tile = bb - 4864; }
        else if (bb < 5888) { in = l3_w; out = l3T;  K = 1024; N = 512;  tile = bb - 5376; }
        else                { in = rpe_ow; out = owT2; K = 64; N = 1536; tile = bb - 5888; }
        float (*tl)[33] = (float(*)[33])smem_raw;
        int tiles_x = N >> 5;
        int n0 = (tile % tiles_x) * 32, k0 = (tile / tiles_x) * 32;
        int tx = t & 31, ty = t >> 5;            // 32 x 8
        #pragma unroll
        for (int r = 0; r < 32; r += 8)
            tl[ty + r][tx] = in[(size_t)(k0 + ty + r) * N + n0 + tx];
        __syncthreads();
        #pragma unroll
        for (int r = 0; r < 32; r += 8)
            out[(size_t)(n0 + ty + r) * K + k0 + tx] = f2b(tl[tx][ty + r]);
    } else if (bb < 5992) {
        int i = (bb - 5984) * 256 + t;
        gluB[i] = (i < 1024) ? l1_b[i] : l2_b[i - 1024];
    } else {
        float (*yb)[64] = (float(*)[64])smem_raw;
        int lane = t & 63;
        int wv = t >> 6;
        int a = (bb - 5992) * 4 + wv;            // 0..4095 = di*64 + dj
        int a1 = a >> 6, a2 = a & 63;
        float di = (a1 < 32) ? (float)a1 : (float)(a1 - 64);
        float dj = (a2 < 32) ? (float)a2 : (float)(a2 - 64);
        float xv = di * pos_w[lane] + dj * pos_w[64 + lane] + pos_b[lane];
        for (int L = 0; L < 3; ++L) {
            float ss = xv * xv;
            #pragma unroll
            for (int o = 32; o > 0; o >>= 1) ss += __shfl_xor(ss, o, 64);
            float yv = silu_f(xv / (sqrtf(ss) * 0.125f + 1e-8f));
            yb[wv][lane] = yv;
            __syncthreads();
            float acc = lb[L * 64 + lane];
            const float* w = lw + L * 4096 + lane;
            #pragma unroll 8
            for (int k = 0; k < 64; ++k) acc = fmaf(yb[wv][k], w[k * 64], acc);
            __syncthreads();
            xv = acc;
        }
        float ss = xv * xv;
        #pragma unroll
        for (int o = 32; o > 0; o >>= 1) ss += __shfl_xor(ss, o, 64);
        float yv = silu_f(xv / (sqrtf(ss) * 0.125f + 1e-8f));
        y[(size_t)a * 64 + lane] = f2b(yv);
    }
}

// ---------------- K2: bf16 MFMA GEMM, 128x128 tile, BK=64, B^T input ----------------
// EPI 0: C0 = bf16(silu(acc+b[col]))     EPI 1: C0 = bf16(acc+b[col]+b2f(R16[idx]))
// EPI 2: C0 = bf16(acc+b[col])           EPI 4: C0 = bf16(silu(acc+b[row]))
// EPI 5: GLU fused epilogue              EPI 6: coefR ring layout * decay (RPE direct)
// EPI 7: C0 = bf16(silu(acc+b[col]) * mixT[col][row])   (mixT via C1)
// PERMB 1: BT row n -> (n&~1023)|((n&31)<<5)|((n>>5)&31)   (position permute)
// PERMB 2: GLU column interleave
// PERMB 3: RPE bit-swap: n -> ((n&63)<<6)|(n>>6)
template<int EPI, int PERMB>
__launch_bounds__(256, 4)
__global__ void mfma_gemm(const u16* __restrict__ A, const u16* __restrict__ BT,
                          const float* __restrict__ bias, const void* __restrict__ R,
                          void* __restrict__ C0, const void* __restrict__ C1,
                          int M, int N, int K) {
    __shared__ __align__(16) u16 Asmem[128 * 64];   // 16KB, XOR-swizzled 16B slots
    __shared__ __align__(16) u16 Bsmem[128 * 64];
    int nwg = gridDim.x * gridDim.y;
    int bid = blockIdx.y * gridDim.x + blockIdx.x;
    int qq = nwg >> 3, rr = nwg & 7;
    int xcd = bid & 7, lid = bid >> 3;
    int swz = (xcd < rr ? xcd * (qq + 1) : rr * (qq + 1) + (xcd - rr) * qq) + lid;
    int bx = swz % gridDim.x, by = swz / gridDim.x;
    int tid = threadIdx.x;
    int w = tid >> 6, lane = tid & 63;
    int lr = lane & 15, kg = lane >> 4;
    int wr = w >> 1, wc = w & 1;                     // 2x2 waves, each 64x64
    int m0 = by * 128, n0 = bx * 128;
    f32x4 acc[4][4] = {};
    for (int k0 = 0; k0 < K; k0 += 64) {
        #pragma unroll
        for (int r = 0; r < 4; ++r) {
            int c4 = (r * 4 + w) * 64 + lane;        // 16B chunk index 0..1023
            int row = c4 >> 3, slot = c4 & 7;
            int sl = slot ^ (row & 7);
            const u16* ga = A + (size_t)(m0 + row) * K + k0 + sl * 8;
            int grow = n0 + row;
            if (PERMB == 1) {
                grow = (grow & ~1023) | ((grow & 31) << 5) | ((grow >> 5) & 31);
            } else if (PERMB == 2) {
                int c = grow & 127;
                int f = ((grow >> 7) << 6) + ((c >> 6) << 5) + (((c >> 5) & 1) << 4) + (c & 15);
                grow = (((c >> 4) & 1) << 10) + f;   // +1024 selects l2 block
            } else if (PERMB == 3) {
                grow = ((grow & 63) << 6) | ((grow >> 6) & 63);
            }
            const u16* gb = BT + (size_t)grow * K + k0 + sl * 8;
            u16* la = Asmem + (r * 4 + w) * 512;
            u16* lb = Bsmem + (r * 4 + w) * 512;
            __builtin_amdgcn_global_load_lds((const __attribute__((address_space(1))) void*)ga,
                                             (__attribute__((address_space(3))) void*)la, 16, 0, 0);
            __builtin_amdgcn_global_load_lds((const __attribute__((address_space(1))) void*)gb,
                                             (__attribute__((address_space(3))) void*)lb, 16, 0, 0);
        }
        __syncthreads();
        #pragma unroll
        for (int kk = 0; kk < 2; ++kk) {
            bf16x8 af[4], bfr[4];
            #pragma unroll
            for (int m = 0; m < 4; ++m) {
                int row = wr * 64 + m * 16 + lr;
                int sl = (kk * 4 + kg) ^ (row & 7);
                af[m] = *reinterpret_cast<const bf16x8*>(&Asmem[row * 64 + sl * 8]);
            }
            #pragma unroll
            for (int n = 0; n < 4; ++n) {
                int row = wc * 64 + n * 16 + lr;
                int sl = (kk * 4 + kg) ^ (row & 7);
                bfr[n] = *reinterpret_cast<const bf16x8*>(&Bsmem[row * 64 + sl * 8]);
            }
            #pragma unroll
            for (int m = 0; m < 4; ++m)
                #pragma unroll
                for (int n = 0; n < 4; ++n)
                    acc[m][n] = __builtin_amdgcn_mfma_f32_16x16x32_bf16(af[m], bfr[n], acc[m][n], 0, 0, 0);
        }
        __syncthreads();
    }
    if (EPI == 5) {
        #pragma unroll
        for (int m = 0; m < 4; ++m) {
            #pragma unroll
            for (int np = 0; np < 2; ++np) {
                int n = np * 2;
                int f = (n0 >> 1) + wc * 32 + np * 16 + lr;
                #pragma unroll
                for (int q = 0; q < 4; ++q) {
                    int row = m0 + wr * 64 + m * 16 + kg * 4 + q;
                    float a1 = acc[m][n][q] + bias[f];
                    float a2 = acc[m][n + 1][q] + bias[1024 + f];
                    ((u16*)C0)[(size_t)row * GLU_ + f] = f2b(silu_f(a1) * a2);
                }
            }
        }
    } else if (EPI == 7) {
        const u16* mixT = (const u16*)C1;
        #pragma unroll
        for (int m = 0; m < 4; ++m) {
            #pragma unroll
            for (int n = 0; n < 4; ++n) {
                int rowbase = m0 + wr * 64 + m * 16 + kg * 4;
                int col = n0 + wc * 64 + n * 16 + lr;
                u16 mv[4];
                *reinterpret_cast<uint2*>(mv) =
                    *reinterpret_cast<const uint2*>(&mixT[(size_t)col * 16384 + rowbase]);
                #pragma unroll
                for (int q = 0; q < 4; ++q) {
                    float vv = acc[m][n][q] + bias[col];
                    ((u16*)C0)[(size_t)(rowbase + q) * N + col] = f2b(silu_f(vv) * b2f(mv[q]));
                }
            }
        }
    } else {
        #pragma unroll
        for (int m = 0; m < 4; ++m) {
            #pragma unroll
            for (int n = 0; n < 4; ++n) {
                #pragma unroll
                for (int q = 0; q < 4; ++q) {
                    int row = m0 + wr * 64 + m * 16 + kg * 4 + q;
                    int col = n0 + wc * 64 + n * 16 + lr;
                    size_t idx = (size_t)row * N + col;
                    if (EPI == 0) {
                        float vv = acc[m][n][q] + bias[col];
                        ((u16*)C0)[idx] = f2b(silu_f(vv));
                    } else if (EPI == 1) {
                        ((u16*)C0)[idx] = f2b(acc[m][n][q] + bias[col] + b2f(((const u16*)R)[idx]));
                    } else if (EPI == 2) {
                        ((u16*)C0)[idx] = f2b(acc[m][n][q] + bias[col]);
                    } else if (EPI == 4) {
                        float vv = acc[m][n][q] + bias[row];
                        ((u16*)C0)[idx] = f2b(silu_f(vv));
                    } else {  // EPI == 6: coefR ring layout, decay fused
                        int dii = col & 63, djj = (col >> 6) & 63;
                        float adi = (dii < 32) ? (float)dii : (float)(64 - dii);
                        float adj = (djj < 32) ? (float)djj : (float)(64 - djj);
                        float decay = __expf(-0.0010005003335835344f * (adi + adj));
                        u16 val = f2b((acc[m][n][q] + bias[row]) * decay);
                        int s = (64 - dii) & 63;
                        size_t base = (size_t)row * 4608 + djj * 72;
                        ((u16*)C0)[base + s] = val;
                        if (s < 8) ((u16*)C0)[base + s + 64] = val;   // doubled ring
                    }
                }
            }
        }
    }
}

// ---------------- K3: per-channel block-Toeplitz mixing via MFMA ----------------
// 2 channels per block, double-buffered v/d2l staging. K-loop: inner 8-slot unroll
// hoists the XOR chunk indices (slot-invariant: (w0&7)=(lr-jj)&7, w1&7==w0&7) out
// of the loop; setprio(1) wraps each slot's MFMA cluster (waves barrier-free here).
__launch_bounds__(512, 1)
__global__ void conv_mfma_kernel(const u16* __restrict__ coefR, const u16* __restrict__ vT2,
                                 u16* __restrict__ mixT) {
    __shared__ __align__(16) u16 vlds[2][16384];   // 2 x 32 KB: [b 16][chunk 128], chunk ^= (b&7)
    __shared__ __align__(16) u16 gt[32768];        // 64 KB: [o 8][w 64][8 chunks], chunk ^= (w&7)
    __shared__ __align__(16) u16 d2l[2][4608];     // 2 x 9 KB: ring [w][72]
    int c0 = blockIdx.x * 2;
    int t = threadIdx.x;
    int wv = t >> 6, lane = t & 63;
    int lr = lane & 15, kg = lane >> 4;
    int lrs = lr & 7;

    int mbc[4];
    #pragma unroll
    for (int nt = 0; nt < 4; ++nt)
        mbc[nt] = (((kg * 8 - (nt * 8 + wv)) & 63) & ~7) >> 3;

    auto stage_v = [&](u16* dstbuf, int ch) {
        #pragma unroll
        for (int pass = 0; pass < 4; ++pass) {
            int L = pass * 512 + t;                  // dest chunk
            int b = L >> 7, k8s = L & 127;
            int k8 = k8s ^ (b & 7);
            const u16* src = vT2 + (size_t)ch * 16384 + b * 1024 + k8 * 8;
            u16* dst = dstbuf + (size_t)(pass * 512 + wv * 64) * 8;   // wave-uniform base
            __builtin_amdgcn_global_load_lds((const __attribute__((address_space(1))) void*)src,
                                             (__attribute__((address_space(3))) void*)dst, 16, 0, 0);
        }
    };
    auto stage_d2l = [&](u16* dstbuf, int ch) {
        const u16* src = coefR + (size_t)ch * 4608 + t * 8;
        u16* dst = dstbuf + wv * 512;
        __builtin_amdgcn_global_load_lds((const __attribute__((address_space(1))) void*)src,
                                         (__attribute__((address_space(3))) void*)dst, 16, 0, 0);
        if (wv == 0) {   // chunks 512..575
            const u16* src2 = coefR + (size_t)ch * 4608 + (512 + lane) * 8;
            u16* dst2 = dstbuf + 4096;
            __builtin_amdgcn_global_load_lds((const __attribute__((address_space(1))) void*)src2,
                                             (__attribute__((address_space(3))) void*)dst2, 16, 0, 0);
        }
    };
    auto build_gt = [&](const u16* d2lbuf) {
        const bf16x8* d2l8 = (const bf16x8*)d2lbuf;
        bf16x8* gt8 = (bf16x8*)gt;
        int oo = (8 - wv) & 7;                    // wave-uniform
        #pragma unroll
        for (int j = 0; j < 8; ++j) {
            int ci = j * 64 + lane;              // chunk within table
            int w = ci >> 3, m8s = ci & 7;
            int m8 = m8s ^ (w & 7);
            bf16x8 A = d2l8[w * 9 + m8];
            bf16x8 Bn = d2l8[w * 9 + m8 + 1];
            u16 av[16], ov[8];
            *reinterpret_cast<bf16x8*>(av) = A;
            *reinterpret_cast<bf16x8*>(av + 8) = Bn;
            #pragma unroll
            for (int e = 0; e < 8; ++e) {
                u16 r = av[e];
                #pragma unroll
                for (int s2 = 1; s2 < 8; ++s2)
                    r = (oo == s2) ? av[e + s2] : r;
                ov[e] = r;
            }
            gt8[wv * 512 + ci] = *reinterpret_cast<bf16x8*>(ov);
        }
    };
    auto kloop = [&](const u16* vbuf, f32x4 (&acc)[4][2]) {
        const bf16x8* vb8 = (const bf16x8*)vbuf;
        const bf16x8* gtw = (const bf16x8*)gt + wv * 512;
        // slot-invariant chunk indices: (w0&7) = (lr-jj)&7, and (w1&7)==(w0&7)
        int cidx[8][4];
        #pragma unroll
        for (int jj = 0; jj < 8; ++jj)
            #pragma unroll
            for (int nt = 0; nt < 4; ++nt)
                cidx[jj][nt] = mbc[nt] ^ ((lr - jj) & 7);
        for (int jp0 = 0; jp0 < 32; jp0 += 8) {
            #pragma unroll
            for (int jj = 0; jj < 8; ++jj) {
                int jp = jp0 + jj;
                bf16x8 af = vb8[lr * 128 + ((jp * 4 + kg) ^ lrs)];
                int w0 = (lr - jp) & 63;
                int w1 = (w0 + 16) & 63;
                __builtin_amdgcn_s_setprio(1);
                #pragma unroll
                for (int nt = 0; nt < 4; ++nt) {
                    bf16x8 b0 = gtw[w0 * 8 + cidx[jj][nt]];
                    acc[nt][0] = __builtin_amdgcn_mfma_f32_16x16x32_bf16(af, b0, acc[nt][0], 0, 0, 0);
                    bf16x8 b1 = gtw[w1 * 8 + cidx[jj][nt]];
                    acc[nt][1] = __builtin_amdgcn_mfma_f32_16x16x32_bf16(af, b1, acc[nt][1], 0, 0, 0);
                }
                __builtin_amdgcn_s_setprio(0);
            }
        }
    };
    auto outstage = [&](u16* vbuf, f32x4 (&acc)[4][2]) {
        #pragma unroll
        for (int nt = 0; nt < 4; ++nt) {
            #pragma unroll
            for (int h = 0; h < 2; ++h) {
                int p = nt * 256 + wv * 32 + h * 16 + lr;
                #pragma unroll
                for (int q = 0; q < 4; ++q) {
                    int b = kg * 4 + q;
                    vbuf[b * 1024 + (p ^ ((b & 7) << 3))] = f2b(acc[nt][h][q]);
                }
            }
        }
    };
    auto copyout = [&](const u16* vbuf, int ch) {
        const uint4* src16 = (const uint4*)vbuf;
        #pragma unroll
        for (int pass = 0; pass < 4; ++pass) {
            int L = pass * 512 + t;
            int b = L >> 7;
            int pc = (L & 127) ^ (b & 7);
            uint4 val = src16[L];
            *reinterpret_cast<uint4*>(mixT + (size_t)ch * 16384 + b * 1024 + pc * 8) = val;
        }
    };

    // prologue: stage ch0 v + both d2l rings
    stage_v(vlds[0], c0);
    stage_d2l(d2l[0], c0);
    stage_d2l(d2l[1], c0 + 1);
    __syncthreads();             // drains all DMA
    build_gt(d2l[0]);
    __syncthreads();             // gt(ch0) visible
    stage_v(vlds[1], c0 + 1);    // in flight across K-loop ch0
    f32x4 accA[4][2] = {};
    kloop(vlds[0], accA);
    __syncthreads();             // drains vlds[1] DMA; all waves done with gt + vlds[0]
    build_gt(d2l[1]);
    outstage(vlds[0], accA);
    __syncthreads();             // gt(ch1) + staged mix(ch0) visible
    copyout(vlds[0], c0);
    f32x4 accB[4][2] = {};
    kloop(vlds[1], accB);
    __syncthreads();             // all waves done with vlds[1]
    outstage(vlds[1], accB);
    __syncthreads();
    copyout(vlds[1], c0 + 1);
}

// ---------------- K6: out = x2b + srms(mm)  (both bf16 in, fp32 out) ----------------
__launch_bounds__(256)
__global__ void final_kernel(const u16* __restrict__ x2b, const u16* __restrict__ m,
                             float* __restrict__ out) {
    int row = blockIdx.x;
    const u16* mr = m + (size_t)row * DIM_;
    const u16* xr = x2b + (size_t)row * DIM_;
    float* orow = out + (size_t)row * DIM_;
    int t = threadIdx.x;
    float a = b2f(mr[t]), b2 = b2f(mr[t + 256]);
    float ss = a * a + b2 * b2;
    #pragma unroll
    for (int o = 32; o > 0; o >>= 1) ss += __shfl_xor(ss, o, 64);
    __shared__ float red[4];
    int wid = t >> 6;
    if ((t & 63) == 0) red[wid] = ss;
    __syncthreads();
    float tot = red[0] + red[1] + red[2] + red[3];
    float inv = 1.0f / (sqrtf(tot) * 0.044194173824159216f + 1e-8f);
    orow[t]       = b2f(xr[t])       + a  * inv;
    orow[t + 256] = b2f(xr[t + 256]) + b2 * inv;
}

extern "C" void kernel_launch(void* const* d_in, const int* in_sizes, int n_in,
                              void* d_out, int out_size, void* d_ws, size_t ws_size,
                              hipStream_t stream) {
    const float* x     = (const float*)d_in[0];
    const float* u_w   = (const float*)d_in[1];
    const float* u_b   = (const float*)d_in[2];
    const float* v_w   = (const float*)d_in[3];
    const float* v_b   = (const float*)d_in[4];
    const float* o_w   = (const float*)d_in[5];
    const float* o_b   = (const float*)d_in[6];
    const float* pos_w = (const float*)d_in[7];
    const float* pos_b = (const float*)d_in[8];
    const float* rpe_lw = (const float*)d_in[9];
    const float* rpe_lb = (const float*)d_in[10];
    const float* rpe_ow = (const float*)d_in[11];
    const float* rpe_ob = (const float*)d_in[12];
    const float* l1_w  = (const float*)d_in[13];
    const float* l1_b  = (const float*)d_in[14];
    const float* l2_w  = (const float*)d_in[15];
    const float* l2_b  = (const float*)d_in[16];
    const float* l3_w  = (const float*)d_in[17];
    const float* l3_b  = (const float*)d_in[18];
    float* out = (float*)d_out;

    // -------- workspace layout (u16 units unless noted) --------
    u16* coefR  = (u16*)d_ws;                  //  7,077,888  (1536 x 4608 ring)
    u16* xb     = coefR + 7077888;             //  8,388,608
    u16* u      = xb + 8388608;                // 25,165,824
    u16* vT2    = u + 25165824;                // 25,165,824  [c][b*1024 + k], k=j'*32+i'
    u16* mixT   = vT2 + 25165824;              // 25,165,824  [c][r]
    u16* x2b    = mixT + 25165824;             //  8,388,608
    u16* uwT    = x2b + 8388608;               //    786,432
    u16* vwT    = uwT + 786432;
    u16* owT    = vwT + 786432;
    u16* gluT   = owT + 786432;                //  1,048,576 (l1T ++ l2T)
    u16* l3T    = gluT + 1048576;              //    524,288
    float* gluB = (float*)(l3T + 524288);      //      2,048 fp32
    u16* y      = (u16*)(gluB + 2048);         //    262,144  (4096 x 64)
    u16* owT2   = y + 262144;                  //     98,304  (1536 x 64)
    // overlays:
    u16* p      = u;                            // 16,777,216 (u dead after o-proj)
    u16* mm     = vT2;                          //  8,388,608 (vT2 dead after conv)

    const int M = B_ * NN;  // 16384

    // 1) fused prep: cvt + all transposes + bias concat + RPE hidden
    prep_kernel<<<7016, 256, 0, stream>>>(x, xb, u_w, uwT, v_w, vwT, o_w, owT,
                                          l1_w, l2_w, gluT, l3_w, l3T, rpe_ow, owT2,
                                          l1_b, l2_b, gluB, pos_w, pos_b, rpe_lw, rpe_lb, y);
    // 2) coefR = ring((rpe_ow^T @ y^T + ob) * decay)  [direct, bit-swap cols]
    mfma_gemm<6, 3><<<dim3(4096 / 128, D1_ / 128), 256, 0, stream>>>(owT2, y, rpe_ob, nullptr, coefR, nullptr, D1_, 4096, 64);
    // 3) vT2 = silu(v_w^T @ x^T) with position-permuted cols  [1536 x 16384 bf16]
    mfma_gemm<4, 1><<<dim3(M / 128, D1_ / 128), 256, 0, stream>>>(vwT, xb, v_b, nullptr, vT2, nullptr, D1_, M, DIM_);
    // 4) token mixing on matrix cores: mixT[c][r]  (2 channels per block, dbuf prefetch)
    conv_mfma_kernel<<<768, 512, 0, stream>>>(coefR, vT2, mixT);
    // 5) u = silu(x@u_w+b) * mix   [mult fused into epilogue]
    mfma_gemm<7, 0><<<dim3(D1_ / 128, M / 128), 256, 0, stream>>>(xb, uwT, u_b, nullptr, u, mixT, M, D1_, DIM_);
    // 6) x2b = bf16(xb + u@o_w + b)   [residual read as bf16]
    mfma_gemm<1, 0><<<dim3(DIM_ / 128, M / 128), 256, 0, stream>>>(u, owT, o_b, xb, x2b, nullptr, M, DIM_, D1_);
    // 7) p = silu(x2b@l1+b1)*(x2b@l2+b2)   [GLU fused, column-interleaved staging]
    mfma_gemm<5, 2><<<dim3(2 * GLU_ / 128, M / 128), 256, 0, stream>>>(x2b, gluT, gluB, nullptr, p, nullptr, M, 2 * GLU_, DIM_);
    // 8) mm = bf16(p@l3 + b3)
    mfma_gemm<2, 0><<<dim3(DIM_ / 128, M / 128), 256, 0, stream>>>(p, l3T, l3_b, nullptr, mm, nullptr, M, DIM_, GLU_);
    // 9) out = x2b + srms(mm)
    final_kernel<<<M, 256, 0, stream>>>(x2b, mm, out);
}

// Round 18
// 329.056 us; speedup vs baseline: 1.6595x; 1.6595x over previous
//
#include <hip/hip_runtime.h>
#include <math.h>

#define B_   16
#define NN   1024
#define DIM_ 512
#define D1_  1536
#define GLU_ 1024

typedef unsigned short u16;
typedef __attribute__((ext_vector_type(8))) short bf16x8;
typedef __attribute__((ext_vector_type(4))) float f32x4;

__device__ __forceinline__ float silu_f(float x) {
    return x / (1.0f + __expf(-x));
}
__device__ __forceinline__ u16 f2b(float f) {           // RNE fp32 -> bf16
    unsigned u = __float_as_uint(f);
    return (u16)((u + 0x7FFF + ((u >> 16) & 1)) >> 16);
}
__device__ __forceinline__ float b2f(u16 s) {
    return __uint_as_float(((unsigned)s) << 16);
}

// ---------------- K0: fused prep (cvt + all transposes + bias concat + RPE hidden MLP) ----------
__launch_bounds__(256)
__global__ void prep_kernel(const float* __restrict__ x, u16* __restrict__ xb,
                            const float* __restrict__ u_w, u16* __restrict__ uwT,
                            const float* __restrict__ v_w, u16* __restrict__ vwT,
                            const float* __restrict__ o_w, u16* __restrict__ owT,
                            const float* __restrict__ l1_w, const float* __restrict__ l2_w,
                            u16* __restrict__ gluT,
                            const float* __restrict__ l3_w, u16* __restrict__ l3T,
                            const float* __restrict__ rpe_ow, u16* __restrict__ owT2,
                            const float* __restrict__ l1_b, const float* __restrict__ l2_b,
                            float* __restrict__ gluB,
                            const float* __restrict__ pos_w, const float* __restrict__ pos_b,
                            const float* __restrict__ lw, const float* __restrict__ lb,
                            u16* __restrict__ y) {
    __shared__ __align__(16) char smem_raw[4352];
    int bb = blockIdx.x;
    int t = threadIdx.x;
    if (bb < 2048) {
        #pragma unroll
        for (int j = 0; j < 4; ++j) {
            int i = bb * 1024 + j * 256 + t;
            float4 f = reinterpret_cast<const float4*>(x)[i];
            unsigned lo = (unsigned)f2b(f.x) | ((unsigned)f2b(f.y) << 16);
            unsigned hi = (unsigned)f2b(f.z) | ((unsigned)f2b(f.w) << 16);
            reinterpret_cast<uint2*>(xb)[i] = make_uint2(lo, hi);
        }
    } else if (bb < 5984) {
        const float* in; u16* out; int K, N, tile;
        if (bb < 2816)      { in = u_w;  out = uwT;  K = 512;  N = 1536; tile = bb - 2048; }
        else if (bb < 3584) { in = v_w;  out = vwT;  K = 512;  N = 1536; tile = bb - 2816; }
        else if (bb < 4352) { in = o_w;  out = owT;  K = 1536; N = 512;  tile = bb - 3584; }
        else if (bb < 4864) { in = l1_w; out = gluT; K = 512;  N = 1024; tile = bb - 4352; }
        else if (bb < 5376) { in = l2_w; out = gluT + (size_t)GLU_ * DIM_; K = 512; N = 1024; tile = bb - 4864; }
        else if (bb < 5888) { in = l3_w; out = l3T;  K = 1024; N = 512;  tile = bb - 5376; }
        else                { in = rpe_ow; out = owT2; K = 64; N = 1536; tile = bb - 5888; }
        float (*tl)[33] = (float(*)[33])smem_raw;
        int tiles_x = N >> 5;
        int n0 = (tile % tiles_x) * 32, k0 = (tile / tiles_x) * 32;
        int tx = t & 31, ty = t >> 5;            // 32 x 8
        #pragma unroll
        for (int r = 0; r < 32; r += 8)
            tl[ty + r][tx] = in[(size_t)(k0 + ty + r) * N + n0 + tx];
        __syncthreads();
        #pragma unroll
        for (int r = 0; r < 32; r += 8)
            out[(size_t)(n0 + ty + r) * K + k0 + tx] = f2b(tl[tx][ty + r]);
    } else if (bb < 5992) {
        int i = (bb - 5984) * 256 + t;
        gluB[i] = (i < 1024) ? l1_b[i] : l2_b[i - 1024];
    } else {
        float (*yb)[64] = (float(*)[64])smem_raw;
        int lane = t & 63;
        int wv = t >> 6;
        int a = (bb - 5992) * 4 + wv;            // 0..4095 = di*64 + dj
        int a1 = a >> 6, a2 = a & 63;
        float di = (a1 < 32) ? (float)a1 : (float)(a1 - 64);
        float dj = (a2 < 32) ? (float)a2 : (float)(a2 - 64);
        float xv = di * pos_w[lane] + dj * pos_w[64 + lane] + pos_b[lane];
        for (int L = 0; L < 3; ++L) {
            float ss = xv * xv;
            #pragma unroll
            for (int o = 32; o > 0; o >>= 1) ss += __shfl_xor(ss, o, 64);
            float yv = silu_f(xv / (sqrtf(ss) * 0.125f + 1e-8f));
            yb[wv][lane] = yv;
            __syncthreads();
            float acc = lb[L * 64 + lane];
            const float* w = lw + L * 4096 + lane;
            #pragma unroll 8
            for (int k = 0; k < 64; ++k) acc = fmaf(yb[wv][k], w[k * 64], acc);
            __syncthreads();
            xv = acc;
        }
        float ss = xv * xv;
        #pragma unroll
        for (int o = 32; o > 0; o >>= 1) ss += __shfl_xor(ss, o, 64);
        float yv = silu_f(xv / (sqrtf(ss) * 0.125f + 1e-8f));
        y[(size_t)a * 64 + lane] = f2b(yv);
    }
}

// ---------------- K2: bf16 MFMA GEMM, 128x128 tile, BK=64, B^T input ----------------
// EPI 0: C0 = bf16(silu(acc+b[col]))     EPI 1: C0 = bf16(acc+b[col]+b2f(R16[idx]))
// EPI 2: C0 = bf16(acc+b[col])           EPI 4: C0 = bf16(silu(acc+b[row]))
// EPI 5: GLU fused epilogue              EPI 6: coefR ring layout * decay (RPE direct)
// EPI 7: C0 = bf16(silu(acc+b[col]) * mixT[col][row])   (mixT via C1)
// PERMB 1: BT row n -> (n&~1023)|((n&31)<<5)|((n>>5)&31)   (position permute)
// PERMB 2: GLU column interleave
// PERMB 3: RPE bit-swap: n -> ((n&63)<<6)|(n>>6)
template<int EPI, int PERMB>
__launch_bounds__(256, 4)
__global__ void mfma_gemm(const u16* __restrict__ A, const u16* __restrict__ BT,
                          const float* __restrict__ bias, const void* __restrict__ R,
                          void* __restrict__ C0, const void* __restrict__ C1,
                          int M, int N, int K) {
    __shared__ __align__(16) u16 Asmem[128 * 64];   // 16KB, XOR-swizzled 16B slots
    __shared__ __align__(16) u16 Bsmem[128 * 64];
    int nwg = gridDim.x * gridDim.y;
    int bid = blockIdx.y * gridDim.x + blockIdx.x;
    int qq = nwg >> 3, rr = nwg & 7;
    int xcd = bid & 7, lid = bid >> 3;
    int swz = (xcd < rr ? xcd * (qq + 1) : rr * (qq + 1) + (xcd - rr) * qq) + lid;
    int bx = swz % gridDim.x, by = swz / gridDim.x;
    int tid = threadIdx.x;
    int w = tid >> 6, lane = tid & 63;
    int lr = lane & 15, kg = lane >> 4;
    int wr = w >> 1, wc = w & 1;                     // 2x2 waves, each 64x64
    int m0 = by * 128, n0 = bx * 128;
    f32x4 acc[4][4] = {};
    for (int k0 = 0; k0 < K; k0 += 64) {
        #pragma unroll
        for (int r = 0; r < 4; ++r) {
            int c4 = (r * 4 + w) * 64 + lane;        // 16B chunk index 0..1023
            int row = c4 >> 3, slot = c4 & 7;
            int sl = slot ^ (row & 7);
            const u16* ga = A + (size_t)(m0 + row) * K + k0 + sl * 8;
            int grow = n0 + row;
            if (PERMB == 1) {
                grow = (grow & ~1023) | ((grow & 31) << 5) | ((grow >> 5) & 31);
            } else if (PERMB == 2) {
                int c = grow & 127;
                int f = ((grow >> 7) << 6) + ((c >> 6) << 5) + (((c >> 5) & 1) << 4) + (c & 15);
                grow = (((c >> 4) & 1) << 10) + f;   // +1024 selects l2 block
            } else if (PERMB == 3) {
                grow = ((grow & 63) << 6) | ((grow >> 6) & 63);
            }
            const u16* gb = BT + (size_t)grow * K + k0 + sl * 8;
            u16* la = Asmem + (r * 4 + w) * 512;
            u16* lb = Bsmem + (r * 4 + w) * 512;
            __builtin_amdgcn_global_load_lds((const __attribute__((address_space(1))) void*)ga,
                                             (__attribute__((address_space(3))) void*)la, 16, 0, 0);
            __builtin_amdgcn_global_load_lds((const __attribute__((address_space(1))) void*)gb,
                                             (__attribute__((address_space(3))) void*)lb, 16, 0, 0);
        }
        __syncthreads();
        #pragma unroll
        for (int kk = 0; kk < 2; ++kk) {
            bf16x8 af[4], bfr[4];
            #pragma unroll
            for (int m = 0; m < 4; ++m) {
                int row = wr * 64 + m * 16 + lr;
                int sl = (kk * 4 + kg) ^ (row & 7);
                af[m] = *reinterpret_cast<const bf16x8*>(&Asmem[row * 64 + sl * 8]);
            }
            #pragma unroll
            for (int n = 0; n < 4; ++n) {
                int row = wc * 64 + n * 16 + lr;
                int sl = (kk * 4 + kg) ^ (row & 7);
                bfr[n] = *reinterpret_cast<const bf16x8*>(&Bsmem[row * 64 + sl * 8]);
            }
            #pragma unroll
            for (int m = 0; m < 4; ++m)
                #pragma unroll
                for (int n = 0; n < 4; ++n)
                    acc[m][n] = __builtin_amdgcn_mfma_f32_16x16x32_bf16(af[m], bfr[n], acc[m][n], 0, 0, 0);
        }
        __syncthreads();
    }
    if (EPI == 5) {
        #pragma unroll
        for (int m = 0; m < 4; ++m) {
            #pragma unroll
            for (int np = 0; np < 2; ++np) {
                int n = np * 2;
                int f = (n0 >> 1) + wc * 32 + np * 16 + lr;
                #pragma unroll
                for (int q = 0; q < 4; ++q) {
                    int row = m0 + wr * 64 + m * 16 + kg * 4 + q;
                    float a1 = acc[m][n][q] + bias[f];
                    float a2 = acc[m][n + 1][q] + bias[1024 + f];
                    ((u16*)C0)[(size_t)row * GLU_ + f] = f2b(silu_f(a1) * a2);
                }
            }
        }
    } else if (EPI == 7) {
        const u16* mixT = (const u16*)C1;
        #pragma unroll
        for (int m = 0; m < 4; ++m) {
            #pragma unroll
            for (int n = 0; n < 4; ++n) {
                int rowbase = m0 + wr * 64 + m * 16 + kg * 4;
                int col = n0 + wc * 64 + n * 16 + lr;
                u16 mv[4];
                *reinterpret_cast<uint2*>(mv) =
                    *reinterpret_cast<const uint2*>(&mixT[(size_t)col * 16384 + rowbase]);
                #pragma unroll
                for (int q = 0; q < 4; ++q) {
                    float vv = acc[m][n][q] + bias[col];
                    ((u16*)C0)[(size_t)(rowbase + q) * N + col] = f2b(silu_f(vv) * b2f(mv[q]));
                }
            }
        }
    } else {
        #pragma unroll
        for (int m = 0; m < 4; ++m) {
            #pragma unroll
            for (int n = 0; n < 4; ++n) {
                #pragma unroll
                for (int q = 0; q < 4; ++q) {
                    int row = m0 + wr * 64 + m * 16 + kg * 4 + q;
                    int col = n0 + wc * 64 + n * 16 + lr;
                    size_t idx = (size_t)row * N + col;
                    if (EPI == 0) {
                        float vv = acc[m][n][q] + bias[col];
                        ((u16*)C0)[idx] = f2b(silu_f(vv));
                    } else if (EPI == 1) {
                        ((u16*)C0)[idx] = f2b(acc[m][n][q] + bias[col] + b2f(((const u16*)R)[idx]));
                    } else if (EPI == 2) {
                        ((u16*)C0)[idx] = f2b(acc[m][n][q] + bias[col]);
                    } else if (EPI == 4) {
                        float vv = acc[m][n][q] + bias[row];
                        ((u16*)C0)[idx] = f2b(silu_f(vv));
                    } else {  // EPI == 6: coefR ring layout, decay fused
                        int dii = col & 63, djj = (col >> 6) & 63;
                        float adi = (dii < 32) ? (float)dii : (float)(64 - dii);
                        float adj = (djj < 32) ? (float)djj : (float)(64 - djj);
                        float decay = __expf(-0.0010005003335835344f * (adi + adj));
                        u16 val = f2b((acc[m][n][q] + bias[row]) * decay);
                        int s = (64 - dii) & 63;
                        size_t base = (size_t)row * 4608 + djj * 72;
                        ((u16*)C0)[base + s] = val;
                        if (s < 8) ((u16*)C0)[base + s + 64] = val;   // doubled ring
                    }
                }
            }
        }
    }
}

// ---------------- K3: per-channel block-Toeplitz mixing via MFMA ----------------
// 2 channels per block, double-buffered v/d2l staging: ch1's DMA is issued before
// ch0's K-loop (no barriers inside) and drains at the sync after it.
__launch_bounds__(512, 1)
__global__ void conv_mfma_kernel(const u16* __restrict__ coefR, const u16* __restrict__ vT2,
                                 u16* __restrict__ mixT) {
    __shared__ __align__(16) u16 vlds[2][16384];   // 2 x 32 KB: [b 16][chunk 128], chunk ^= (b&7)
    __shared__ __align__(16) u16 gt[32768];        // 64 KB: [o 8][w 64][8 chunks], chunk ^= (w&7)
    __shared__ __align__(16) u16 d2l[2][4608];     // 2 x 9 KB: ring [w][72]
    int c0 = blockIdx.x * 2;
    int t = threadIdx.x;
    int wv = t >> 6, lane = t & 63;
    int lr = lane & 15, kg = lane >> 4;
    int lrs = lr & 7;

    int mbc[4];
    #pragma unroll
    for (int nt = 0; nt < 4; ++nt)
        mbc[nt] = (((kg * 8 - (nt * 8 + wv)) & 63) & ~7) >> 3;

    auto stage_v = [&](u16* dstbuf, int ch) {
        #pragma unroll
        for (int pass = 0; pass < 4; ++pass) {
            int L = pass * 512 + t;                  // dest chunk
            int b = L >> 7, k8s = L & 127;
            int k8 = k8s ^ (b & 7);
            const u16* src = vT2 + (size_t)ch * 16384 + b * 1024 + k8 * 8;
            u16* dst = dstbuf + (size_t)(pass * 512 + wv * 64) * 8;   // wave-uniform base
            __builtin_amdgcn_global_load_lds((const __attribute__((address_space(1))) void*)src,
                                             (__attribute__((address_space(3))) void*)dst, 16, 0, 0);
        }
    };
    auto stage_d2l = [&](u16* dstbuf, int ch) {
        const u16* src = coefR + (size_t)ch * 4608 + t * 8;
        u16* dst = dstbuf + wv * 512;
        __builtin_amdgcn_global_load_lds((const __attribute__((address_space(1))) void*)src,
                                         (__attribute__((address_space(3))) void*)dst, 16, 0, 0);
        if (wv == 0) {   // chunks 512..575
            const u16* src2 = coefR + (size_t)ch * 4608 + (512 + lane) * 8;
            u16* dst2 = dstbuf + 4096;
            __builtin_amdgcn_global_load_lds((const __attribute__((address_space(1))) void*)src2,
                                             (__attribute__((address_space(3))) void*)dst2, 16, 0, 0);
        }
    };
    auto build_gt = [&](const u16* d2lbuf) {
        const bf16x8* d2l8 = (const bf16x8*)d2lbuf;
        bf16x8* gt8 = (bf16x8*)gt;
        int oo = (8 - wv) & 7;                    // wave-uniform
        #pragma unroll
        for (int j = 0; j < 8; ++j) {
            int ci = j * 64 + lane;              // chunk within table
            int w = ci >> 3, m8s = ci & 7;
            int m8 = m8s ^ (w & 7);
            bf16x8 A = d2l8[w * 9 + m8];
            bf16x8 Bn = d2l8[w * 9 + m8 + 1];
            u16 av[16], ov[8];
            *reinterpret_cast<bf16x8*>(av) = A;
            *reinterpret_cast<bf16x8*>(av + 8) = Bn;
            #pragma unroll
            for (int e = 0; e < 8; ++e) {
                u16 r = av[e];
                #pragma unroll
                for (int s2 = 1; s2 < 8; ++s2)
                    r = (oo == s2) ? av[e + s2] : r;
                ov[e] = r;
            }
            gt8[wv * 512 + ci] = *reinterpret_cast<bf16x8*>(ov);
        }
    };
    auto kloop = [&](const u16* vbuf, f32x4 (&acc)[4][2]) {
        const bf16x8* vb8 = (const bf16x8*)vbuf;
        const bf16x8* gtw = (const bf16x8*)gt + wv * 512;
        for (int jp = 0; jp < 32; ++jp) {
            bf16x8 af = vb8[lr * 128 + ((jp * 4 + kg) ^ lrs)];
            int w0 = (lr - jp) & 63;
            int w1 = (w0 + 16) & 63;
            #pragma unroll
            for (int nt = 0; nt < 4; ++nt) {
                bf16x8 b0 = gtw[w0 * 8 + (mbc[nt] ^ (w0 & 7))];
                acc[nt][0] = __builtin_amdgcn_mfma_f32_16x16x32_bf16(af, b0, acc[nt][0], 0, 0, 0);
                bf16x8 b1 = gtw[w1 * 8 + (mbc[nt] ^ (w1 & 7))];
                acc[nt][1] = __builtin_amdgcn_mfma_f32_16x16x32_bf16(af, b1, acc[nt][1], 0, 0, 0);
            }
        }
    };
    auto outstage = [&](u16* vbuf, f32x4 (&acc)[4][2]) {
        #pragma unroll
        for (int nt = 0; nt < 4; ++nt) {
            #pragma unroll
            for (int h = 0; h < 2; ++h) {
                int p = nt * 256 + wv * 32 + h * 16 + lr;
                #pragma unroll
                for (int q = 0; q < 4; ++q) {
                    int b = kg * 4 + q;
                    vbuf[b * 1024 + (p ^ ((b & 7) << 3))] = f2b(acc[nt][h][q]);
                }
            }
        }
    };
    auto copyout = [&](const u16* vbuf, int ch) {
        const uint4* src16 = (const uint4*)vbuf;
        #pragma unroll
        for (int pass = 0; pass < 4; ++pass) {
            int L = pass * 512 + t;
            int b = L >> 7;
            int pc = (L & 127) ^ (b & 7);
            uint4 val = src16[L];
            *reinterpret_cast<uint4*>(mixT + (size_t)ch * 16384 + b * 1024 + pc * 8) = val;
        }
    };

    // prologue: stage ch0 v + both d2l rings
    stage_v(vlds[0], c0);
    stage_d2l(d2l[0], c0);
    stage_d2l(d2l[1], c0 + 1);
    __syncthreads();             // drains all DMA
    build_gt(d2l[0]);
    __syncthreads();             // gt(ch0) visible
    stage_v(vlds[1], c0 + 1);    // in flight across K-loop ch0
    f32x4 accA[4][2] = {};
    kloop(vlds[0], accA);
    __syncthreads();             // drains vlds[1] DMA; all waves done with gt + vlds[0]
    build_gt(d2l[1]);
    outstage(vlds[0], accA);
    __syncthreads();             // gt(ch1) + staged mix(ch0) visible
    copyout(vlds[0], c0);
    f32x4 accB[4][2] = {};
    kloop(vlds[1], accB);
    __syncthreads();             // all waves done with vlds[1]
    outstage(vlds[1], accB);
    __syncthreads();
    copyout(vlds[1], c0 + 1);
}

// ---------------- K6: out = x2b + srms(mm)  (both bf16 in, fp32 out) ----------------
__launch_bounds__(256)
__global__ void final_kernel(const u16* __restrict__ x2b, const u16* __restrict__ m,
                             float* __restrict__ out) {
    int row = blockIdx.x;
    const u16* mr = m + (size_t)row * DIM_;
    const u16* xr = x2b + (size_t)row * DIM_;
    float* orow = out + (size_t)row * DIM_;
    int t = threadIdx.x;
    float a = b2f(mr[t]), b2 = b2f(mr[t + 256]);
    float ss = a * a + b2 * b2;
    #pragma unroll
    for (int o = 32; o > 0; o >>= 1) ss += __shfl_xor(ss, o, 64);
    __shared__ float red[4];
    int wid = t >> 6;
    if ((t & 63) == 0) red[wid] = ss;
    __syncthreads();
    float tot = red[0] + red[1] + red[2] + red[3];
    float inv = 1.0f / (sqrtf(tot) * 0.044194173824159216f + 1e-8f);
    orow[t]       = b2f(xr[t])       + a  * inv;
    orow[t + 256] = b2f(xr[t + 256]) + b2 * inv;
}

extern "C" void kernel_launch(void* const* d_in, const int* in_sizes, int n_in,
                              void* d_out, int out_size, void* d_ws, size_t ws_size,
                              hipStream_t stream) {
    const float* x     = (const float*)d_in[0];
    const float* u_w   = (const float*)d_in[1];
    const float* u_b   = (const float*)d_in[2];
    const float* v_w   = (const float*)d_in[3];
    const float* v_b   = (const float*)d_in[4];
    const float* o_w   = (const float*)d_in[5];
    const float* o_b   = (const float*)d_in[6];
    const float* pos_w = (const float*)d_in[7];
    const float* pos_b = (const float*)d_in[8];
    const float* rpe_lw = (const float*)d_in[9];
    const float* rpe_lb = (const float*)d_in[10];
    const float* rpe_ow = (const float*)d_in[11];
    const float* rpe_ob = (const float*)d_in[12];
    const float* l1_w  = (const float*)d_in[13];
    const float* l1_b  = (const float*)d_in[14];
    const float* l2_w  = (const float*)d_in[15];
    const float* l2_b  = (const float*)d_in[16];
    const float* l3_w  = (const float*)d_in[17];
    const float* l3_b  = (const float*)d_in[18];
    float* out = (float*)d_out;

    // -------- workspace layout (u16 units unless noted) --------
    u16* coefR  = (u16*)d_ws;                  //  7,077,888  (1536 x 4608 ring)
    u16* xb     = coefR + 7077888;             //  8,388,608
    u16* u      = xb + 8388608;                // 25,165,824
    u16* vT2    = u + 25165824;                // 25,165,824  [c][b*1024 + k], k=j'*32+i'
    u16* mixT   = vT2 + 25165824;              // 25,165,824  [c][r]
    u16* x2b    = mixT + 25165824;             //  8,388,608
    u16* uwT    = x2b + 8388608;               //    786,432
    u16* vwT    = uwT + 786432;
    u16* owT    = vwT + 786432;
    u16* gluT   = owT + 786432;                //  1,048,576 (l1T ++ l2T)
    u16* l3T    = gluT + 1048576;              //    524,288
    float* gluB = (float*)(l3T + 524288);      //      2,048 fp32
    u16* y      = (u16*)(gluB + 2048);         //    262,144  (4096 x 64)
    u16* owT2   = y + 262144;                  //     98,304  (1536 x 64)
    // overlays:
    u16* p      = u;                            // 16,777,216 (u dead after o-proj)
    u16* mm     = vT2;                          //  8,388,608 (vT2 dead after conv)

    const int M = B_ * NN;  // 16384

    // 1) fused prep: cvt + all transposes + bias concat + RPE hidden
    prep_kernel<<<7016, 256, 0, stream>>>(x, xb, u_w, uwT, v_w, vwT, o_w, owT,
                                          l1_w, l2_w, gluT, l3_w, l3T, rpe_ow, owT2,
                                          l1_b, l2_b, gluB, pos_w, pos_b, rpe_lw, rpe_lb, y);
    // 2) coefR = ring((rpe_ow^T @ y^T + ob) * decay)  [direct, bit-swap cols]
    mfma_gemm<6, 3><<<dim3(4096 / 128, D1_ / 128), 256, 0, stream>>>(owT2, y, rpe_ob, nullptr, coefR, nullptr, D1_, 4096, 64);
    // 3) vT2 = silu(v_w^T @ x^T) with position-permuted cols  [1536 x 16384 bf16]
    mfma_gemm<4, 1><<<dim3(M / 128, D1_ / 128), 256, 0, stream>>>(vwT, xb, v_b, nullptr, vT2, nullptr, D1_, M, DIM_);
    // 4) token mixing on matrix cores: mixT[c][r]  (2 channels per block, dbuf prefetch)
    conv_mfma_kernel<<<768, 512, 0, stream>>>(coefR, vT2, mixT);
    // 5) u = silu(x@u_w+b) * mix   [mult fused into epilogue]
    mfma_gemm<7, 0><<<dim3(D1_ / 128, M / 128), 256, 0, stream>>>(xb, uwT, u_b, nullptr, u, mixT, M, D1_, DIM_);
    // 6) x2b = bf16(xb + u@o_w + b)   [residual read as bf16]
    mfma_gemm<1, 0><<<dim3(DIM_ / 128, M / 128), 256, 0, stream>>>(u, owT, o_b, xb, x2b, nullptr, M, DIM_, D1_);
    // 7) p = silu(x2b@l1+b1)*(x2b@l2+b2)   [GLU fused, column-interleaved staging]
    mfma_gemm<5, 2><<<dim3(2 * GLU_ / 128, M / 128), 256, 0, stream>>>(x2b, gluT, gluB, nullptr, p, nullptr, M, 2 * GLU_, DIM_);
    // 8) mm = bf16(p@l3 + b3)
    mfma_gemm<2, 0><<<dim3(DIM_ / 128, M / 128), 256, 0, stream>>>(p, l3T, l3_b, nullptr, mm, nullptr, M, DIM_, GLU_);
    // 9) out = x2b + srms(mm)
    final_kernel<<<M, 256, 0, stream>>>(x2b, mm, out);
}

// Round 19
// 325.708 us; speedup vs baseline: 1.6766x; 1.0103x over previous
//
#include <hip/hip_runtime.h>
#include <math.h>

#define B_   16
#define NN   1024
#define DIM_ 512
#define D1_  1536
#define GLU_ 1024

typedef unsigned short u16;
typedef __attribute__((ext_vector_type(8))) short bf16x8;
typedef __attribute__((ext_vector_type(4))) float f32x4;

__device__ __forceinline__ float silu_f(float x) {
    return x / (1.0f + __expf(-x));
}
__device__ __forceinline__ u16 f2b(float f) {           // RNE fp32 -> bf16
    unsigned u = __float_as_uint(f);
    return (u16)((u + 0x7FFF + ((u >> 16) & 1)) >> 16);
}
__device__ __forceinline__ float b2f(u16 s) {
    return __uint_as_float(((unsigned)s) << 16);
}

// ---------------- K0: fused prep (cvt + all transposes + bias concat + RPE hidden MLP) ----------
__launch_bounds__(256)
__global__ void prep_kernel(const float* __restrict__ x, u16* __restrict__ xb,
                            const float* __restrict__ u_w, u16* __restrict__ uwT,
                            const float* __restrict__ v_w, u16* __restrict__ vwT,
                            const float* __restrict__ o_w, u16* __restrict__ owT,
                            const float* __restrict__ l1_w, const float* __restrict__ l2_w,
                            u16* __restrict__ gluT,
                            const float* __restrict__ l3_w, u16* __restrict__ l3T,
                            const float* __restrict__ rpe_ow, u16* __restrict__ owT2,
                            const float* __restrict__ l1_b, const float* __restrict__ l2_b,
                            float* __restrict__ gluB,
                            const float* __restrict__ pos_w, const float* __restrict__ pos_b,
                            const float* __restrict__ lw, const float* __restrict__ lb,
                            u16* __restrict__ y) {
    __shared__ __align__(16) char smem_raw[4352];
    int bb = blockIdx.x;
    int t = threadIdx.x;
    if (bb < 2048) {
        #pragma unroll
        for (int j = 0; j < 4; ++j) {
            int i = bb * 1024 + j * 256 + t;
            float4 f = reinterpret_cast<const float4*>(x)[i];
            unsigned lo = (unsigned)f2b(f.x) | ((unsigned)f2b(f.y) << 16);
            unsigned hi = (unsigned)f2b(f.z) | ((unsigned)f2b(f.w) << 16);
            reinterpret_cast<uint2*>(xb)[i] = make_uint2(lo, hi);
        }
    } else if (bb < 5984) {
        const float* in; u16* out; int K, N, tile;
        if (bb < 2816)      { in = u_w;  out = uwT;  K = 512;  N = 1536; tile = bb - 2048; }
        else if (bb < 3584) { in = v_w;  out = vwT;  K = 512;  N = 1536; tile = bb - 2816; }
        else if (bb < 4352) { in = o_w;  out = owT;  K = 1536; N = 512;  tile = bb - 3584; }
        else if (bb < 4864) { in = l1_w; out = gluT; K = 512;  N = 1024; tile = bb - 4352; }
        else if (bb < 5376) { in = l2_w; out = gluT + (size_t)GLU_ * DIM_; K = 512; N = 1024; tile = bb - 4864; }
        else if (bb < 5888) { in = l3_w; out = l3T;  K = 1024; N = 512;  tile = bb - 5376; }
        else                { in = rpe_ow; out = owT2; K = 64; N = 1536; tile = bb - 5888; }
        float (*tl)[33] = (float(*)[33])smem_raw;
        int tiles_x = N >> 5;
        int n0 = (tile % tiles_x) * 32, k0 = (tile / tiles_x) * 32;
        int tx = t & 31, ty = t >> 5;            // 32 x 8
        #pragma unroll
        for (int r = 0; r < 32; r += 8)
            tl[ty + r][tx] = in[(size_t)(k0 + ty + r) * N + n0 + tx];
        __syncthreads();
        #pragma unroll
        for (int r = 0; r < 32; r += 8)
            out[(size_t)(n0 + ty + r) * K + k0 + tx] = f2b(tl[tx][ty + r]);
    } else if (bb < 5992) {
        int i = (bb - 5984) * 256 + t;
        gluB[i] = (i < 1024) ? l1_b[i] : l2_b[i - 1024];
    } else {
        float (*yb)[64] = (float(*)[64])smem_raw;
        int lane = t & 63;
        int wv = t >> 6;
        int a = (bb - 5992) * 4 + wv;            // 0..4095 = di*64 + dj
        int a1 = a >> 6, a2 = a & 63;
        float di = (a1 < 32) ? (float)a1 : (float)(a1 - 64);
        float dj = (a2 < 32) ? (float)a2 : (float)(a2 - 64);
        float xv = di * pos_w[lane] + dj * pos_w[64 + lane] + pos_b[lane];
        for (int L = 0; L < 3; ++L) {
            float ss = xv * xv;
            #pragma unroll
            for (int o = 32; o > 0; o >>= 1) ss += __shfl_xor(ss, o, 64);
            float yv = silu_f(xv / (sqrtf(ss) * 0.125f + 1e-8f));
            yb[wv][lane] = yv;
            __syncthreads();
            float acc = lb[L * 64 + lane];
            const float* w = lw + L * 4096 + lane;
            #pragma unroll 8
            for (int k = 0; k < 64; ++k) acc = fmaf(yb[wv][k], w[k * 64], acc);
            __syncthreads();
            xv = acc;
        }
        float ss = xv * xv;
        #pragma unroll
        for (int o = 32; o > 0; o >>= 1) ss += __shfl_xor(ss, o, 64);
        float yv = silu_f(xv / (sqrtf(ss) * 0.125f + 1e-8f));
        y[(size_t)a * 64 + lane] = f2b(yv);
    }
}

// ---------------- K2: bf16 MFMA GEMM, 128x128 tile, BK=64, B^T input ----------------
// EPI 0: C0 = bf16(silu(acc+b[col]))     EPI 1: C0 = bf16(acc+b[col]+b2f(R16[idx]))
// EPI 2: C0 = bf16(acc+b[col])           EPI 4: C0 = bf16(silu(acc+b[row]))
// EPI 5: GLU fused epilogue              EPI 6: coefR ring layout * decay (RPE direct)
// EPI 7: C0 = bf16(silu(acc+b[col]) * mix[col][row]); mix tile LDS-staged (coalesced)
// PERMB 1: BT row n -> (n&~1023)|((n&31)<<5)|((n>>5)&31)   (position permute)
// PERMB 2: GLU column interleave
// PERMB 3: RPE bit-swap: n -> ((n&63)<<6)|(n>>6)
template<int EPI, int PERMB>
__launch_bounds__(256, 4)
__global__ void mfma_gemm(const u16* __restrict__ A, const u16* __restrict__ BT,
                          const float* __restrict__ bias, const void* __restrict__ R,
                          void* __restrict__ C0, const void* __restrict__ C1,
                          int M, int N, int K) {
    __shared__ __align__(16) u16 smemU[16384];      // 32KB: Asmem ++ Bsmem; reused by EPI7
    u16* Asmem = smemU;
    u16* Bsmem = smemU + 8192;
    int nwg = gridDim.x * gridDim.y;
    int bid = blockIdx.y * gridDim.x + blockIdx.x;
    int qq = nwg >> 3, rr = nwg & 7;
    int xcd = bid & 7, lid = bid >> 3;
    int swz = (xcd < rr ? xcd * (qq + 1) : rr * (qq + 1) + (xcd - rr) * qq) + lid;
    int bx = swz % gridDim.x, by = swz / gridDim.x;
    int tid = threadIdx.x;
    int w = tid >> 6, lane = tid & 63;
    int lr = lane & 15, kg = lane >> 4;
    int wr = w >> 1, wc = w & 1;                     // 2x2 waves, each 64x64
    int m0 = by * 128, n0 = bx * 128;
    f32x4 acc[4][4] = {};
    for (int k0 = 0; k0 < K; k0 += 64) {
        #pragma unroll
        for (int r = 0; r < 4; ++r) {
            int c4 = (r * 4 + w) * 64 + lane;        // 16B chunk index 0..1023
            int row = c4 >> 3, slot = c4 & 7;
            int sl = slot ^ (row & 7);
            const u16* ga = A + (size_t)(m0 + row) * K + k0 + sl * 8;
            int grow = n0 + row;
            if (PERMB == 1) {
                grow = (grow & ~1023) | ((grow & 31) << 5) | ((grow >> 5) & 31);
            } else if (PERMB == 2) {
                int c = grow & 127;
                int f = ((grow >> 7) << 6) + ((c >> 6) << 5) + (((c >> 5) & 1) << 4) + (c & 15);
                grow = (((c >> 4) & 1) << 10) + f;   // +1024 selects l2 block
            } else if (PERMB == 3) {
                grow = ((grow & 63) << 6) | ((grow >> 6) & 63);
            }
            const u16* gb = BT + (size_t)grow * K + k0 + sl * 8;
            u16* la = Asmem + (r * 4 + w) * 512;
            u16* lb = Bsmem + (r * 4 + w) * 512;
            __builtin_amdgcn_global_load_lds((const __attribute__((address_space(1))) void*)ga,
                                             (__attribute__((address_space(3))) void*)la, 16, 0, 0);
            __builtin_amdgcn_global_load_lds((const __attribute__((address_space(1))) void*)gb,
                                             (__attribute__((address_space(3))) void*)lb, 16, 0, 0);
        }
        __syncthreads();
        #pragma unroll
        for (int kk = 0; kk < 2; ++kk) {
            bf16x8 af[4], bfr[4];
            #pragma unroll
            for (int m = 0; m < 4; ++m) {
                int row = wr * 64 + m * 16 + lr;
                int sl = (kk * 4 + kg) ^ (row & 7);
                af[m] = *reinterpret_cast<const bf16x8*>(&Asmem[row * 64 + sl * 8]);
            }
            #pragma unroll
            for (int n = 0; n < 4; ++n) {
                int row = wc * 64 + n * 16 + lr;
                int sl = (kk * 4 + kg) ^ (row & 7);
                bfr[n] = *reinterpret_cast<const bf16x8*>(&Bsmem[row * 64 + sl * 8]);
            }
            #pragma unroll
            for (int m = 0; m < 4; ++m)
                #pragma unroll
                for (int n = 0; n < 4; ++n)
                    acc[m][n] = __builtin_amdgcn_mfma_f32_16x16x32_bf16(af[m], bfr[n], acc[m][n], 0, 0, 0);
        }
        __syncthreads();
    }
    if (EPI == 5) {
        #pragma unroll
        for (int m = 0; m < 4; ++m) {
            #pragma unroll
            for (int np = 0; np < 2; ++np) {
                int n = np * 2;
                int f = (n0 >> 1) + wc * 32 + np * 16 + lr;
                #pragma unroll
                for (int q = 0; q < 4; ++q) {
                    int row = m0 + wr * 64 + m * 16 + kg * 4 + q;
                    float a1 = acc[m][n][q] + bias[f];
                    float a2 = acc[m][n + 1][q] + bias[1024 + f];
                    ((u16*)C0)[(size_t)row * GLU_ + f] = f2b(silu_f(a1) * a2);
                }
            }
        }
    } else if (EPI == 7) {
        // stage mix tile [col 128][slot16 16] into dead smemU, swizzled (slot16 ^= col&15)
        const u16* mixTg = (const u16*)C1;
        #pragma unroll
        for (int pass = 0; pass < 8; ++pass) {
            int L = pass * 256 + tid;                // 16B chunk 0..2047
            int colL = L >> 4, s16 = L & 15;
            const u16* srcm = mixTg + (size_t)(n0 + colL) * 16384 + m0 + (s16 ^ (colL & 15)) * 8;
            u16* dstm = smemU + (size_t)(pass * 256 + w * 64) * 8;   // wave-uniform base
            __builtin_amdgcn_global_load_lds((const __attribute__((address_space(1))) void*)srcm,
                                             (__attribute__((address_space(3))) void*)dstm, 16, 0, 0);
        }
        __syncthreads();
        #pragma unroll
        for (int m = 0; m < 4; ++m) {
            #pragma unroll
            for (int n = 0; n < 4; ++n) {
                int colL = wc * 64 + n * 16 + lr;
                int rowL = wr * 64 + m * 16 + kg * 4;
                int idx16 = colL * 128 + (((rowL >> 3) ^ (colL & 15)) * 8) + (rowL & 7);
                u16 mv[4];
                *reinterpret_cast<uint2*>(mv) = *reinterpret_cast<const uint2*>(&smemU[idx16]);
                int col = n0 + colL;
                int rowbase = m0 + rowL;
                #pragma unroll
                for (int q = 0; q < 4; ++q) {
                    float vv = acc[m][n][q] + bias[col];
                    ((u16*)C0)[(size_t)(rowbase + q) * N + col] = f2b(silu_f(vv) * b2f(mv[q]));
                }
            }
        }
    } else {
        #pragma unroll
        for (int m = 0; m < 4; ++m) {
            #pragma unroll
            for (int n = 0; n < 4; ++n) {
                #pragma unroll
                for (int q = 0; q < 4; ++q) {
                    int row = m0 + wr * 64 + m * 16 + kg * 4 + q;
                    int col = n0 + wc * 64 + n * 16 + lr;
                    size_t idx = (size_t)row * N + col;
                    if (EPI == 0) {
                        float vv = acc[m][n][q] + bias[col];
                        ((u16*)C0)[idx] = f2b(silu_f(vv));
                    } else if (EPI == 1) {
                        ((u16*)C0)[idx] = f2b(acc[m][n][q] + bias[col] + b2f(((const u16*)R)[idx]));
                    } else if (EPI == 2) {
                        ((u16*)C0)[idx] = f2b(acc[m][n][q] + bias[col]);
                    } else if (EPI == 4) {
                        float vv = acc[m][n][q] + bias[row];
                        ((u16*)C0)[idx] = f2b(silu_f(vv));
                    } else {  // EPI == 6: coefR ring layout, decay fused
                        int dii = col & 63, djj = (col >> 6) & 63;
                        float adi = (dii < 32) ? (float)dii : (float)(64 - dii);
                        float adj = (djj < 32) ? (float)djj : (float)(64 - djj);
                        float decay = __expf(-0.0010005003335835344f * (adi + adj));
                        u16 val = f2b((acc[m][n][q] + bias[row]) * decay);
                        int s = (64 - dii) & 63;
                        size_t base = (size_t)row * 4608 + djj * 72;
                        ((u16*)C0)[base + s] = val;
                        if (s < 8) ((u16*)C0)[base + s + 64] = val;   // doubled ring
                    }
                }
            }
        }
    }
}

// ---------------- K3: per-channel block-Toeplitz mixing via MFMA ----------------
// 2 channels per block, double-buffered v/d2l staging: ch1's DMA is issued before
// ch0's K-loop (no barriers inside) and drains at the sync after it.
__launch_bounds__(512, 1)
__global__ void conv_mfma_kernel(const u16* __restrict__ coefR, const u16* __restrict__ vT2,
                                 u16* __restrict__ mixT) {
    __shared__ __align__(16) u16 vlds[2][16384];   // 2 x 32 KB: [b 16][chunk 128], chunk ^= (b&7)
    __shared__ __align__(16) u16 gt[32768];        // 64 KB: [o 8][w 64][8 chunks], chunk ^= (w&7)
    __shared__ __align__(16) u16 d2l[2][4608];     // 2 x 9 KB: ring [w][72]
    int c0 = blockIdx.x * 2;
    int t = threadIdx.x;
    int wv = t >> 6, lane = t & 63;
    int lr = lane & 15, kg = lane >> 4;
    int lrs = lr & 7;

    int mbc[4];
    #pragma unroll
    for (int nt = 0; nt < 4; ++nt)
        mbc[nt] = (((kg * 8 - (nt * 8 + wv)) & 63) & ~7) >> 3;

    auto stage_v = [&](u16* dstbuf, int ch) {
        #pragma unroll
        for (int pass = 0; pass < 4; ++pass) {
            int L = pass * 512 + t;                  // dest chunk
            int b = L >> 7, k8s = L & 127;
            int k8 = k8s ^ (b & 7);
            const u16* src = vT2 + (size_t)ch * 16384 + b * 1024 + k8 * 8;
            u16* dst = dstbuf + (size_t)(pass * 512 + wv * 64) * 8;   // wave-uniform base
            __builtin_amdgcn_global_load_lds((const __attribute__((address_space(1))) void*)src,
                                             (__attribute__((address_space(3))) void*)dst, 16, 0, 0);
        }
    };
    auto stage_d2l = [&](u16* dstbuf, int ch) {
        const u16* src = coefR + (size_t)ch * 4608 + t * 8;
        u16* dst = dstbuf + wv * 512;
        __builtin_amdgcn_global_load_lds((const __attribute__((address_space(1))) void*)src,
                                         (__attribute__((address_space(3))) void*)dst, 16, 0, 0);
        if (wv == 0) {   // chunks 512..575
            const u16* src2 = coefR + (size_t)ch * 4608 + (512 + lane) * 8;
            u16* dst2 = dstbuf + 4096;
            __builtin_amdgcn_global_load_lds((const __attribute__((address_space(1))) void*)src2,
                                             (__attribute__((address_space(3))) void*)dst2, 16, 0, 0);
        }
    };
    auto build_gt = [&](const u16* d2lbuf) {
        const bf16x8* d2l8 = (const bf16x8*)d2lbuf;
        bf16x8* gt8 = (bf16x8*)gt;
        int oo = (8 - wv) & 7;                    // wave-uniform
        #pragma unroll
        for (int j = 0; j < 8; ++j) {
            int ci = j * 64 + lane;              // chunk within table
            int w = ci >> 3, m8s = ci & 7;
            int m8 = m8s ^ (w & 7);
            bf16x8 A = d2l8[w * 9 + m8];
            bf16x8 Bn = d2l8[w * 9 + m8 + 1];
            u16 av[16], ov[8];
            *reinterpret_cast<bf16x8*>(av) = A;
            *reinterpret_cast<bf16x8*>(av + 8) = Bn;
            #pragma unroll
            for (int e = 0; e < 8; ++e) {
                u16 r = av[e];
                #pragma unroll
                for (int s2 = 1; s2 < 8; ++s2)
                    r = (oo == s2) ? av[e + s2] : r;
                ov[e] = r;
            }
            gt8[wv * 512 + ci] = *reinterpret_cast<bf16x8*>(ov);
        }
    };
    auto kloop = [&](const u16* vbuf, f32x4 (&acc)[4][2]) {
        const bf16x8* vb8 = (const bf16x8*)vbuf;
        const bf16x8* gtw = (const bf16x8*)gt + wv * 512;
        for (int jp = 0; jp < 32; ++jp) {
            bf16x8 af = vb8[lr * 128 + ((jp * 4 + kg) ^ lrs)];
            int w0 = (lr - jp) & 63;
            int w1 = (w0 + 16) & 63;
            #pragma unroll
            for (int nt = 0; nt < 4; ++nt) {
                bf16x8 b0 = gtw[w0 * 8 + (mbc[nt] ^ (w0 & 7))];
                acc[nt][0] = __builtin_amdgcn_mfma_f32_16x16x32_bf16(af, b0, acc[nt][0], 0, 0, 0);
                bf16x8 b1 = gtw[w1 * 8 + (mbc[nt] ^ (w1 & 7))];
                acc[nt][1] = __builtin_amdgcn_mfma_f32_16x16x32_bf16(af, b1, acc[nt][1], 0, 0, 0);
            }
        }
    };
    auto outstage = [&](u16* vbuf, f32x4 (&acc)[4][2]) {
        #pragma unroll
        for (int nt = 0; nt < 4; ++nt) {
            #pragma unroll
            for (int h = 0; h < 2; ++h) {
                int p = nt * 256 + wv * 32 + h * 16 + lr;
                #pragma unroll
                for (int q = 0; q < 4; ++q) {
                    int b = kg * 4 + q;
                    vbuf[b * 1024 + (p ^ ((b & 7) << 3))] = f2b(acc[nt][h][q]);
                }
            }
        }
    };
    auto copyout = [&](const u16* vbuf, int ch) {
        const uint4* src16 = (const uint4*)vbuf;
        #pragma unroll
        for (int pass = 0; pass < 4; ++pass) {
            int L = pass * 512 + t;
            int b = L >> 7;
            int pc = (L & 127) ^ (b & 7);
            uint4 val = src16[L];
            *reinterpret_cast<uint4*>(mixT + (size_t)ch * 16384 + b * 1024 + pc * 8) = val;
        }
    };

    // prologue: stage ch0 v + both d2l rings
    stage_v(vlds[0], c0);
    stage_d2l(d2l[0], c0);
    stage_d2l(d2l[1], c0 + 1);
    __syncthreads();             // drains all DMA
    build_gt(d2l[0]);
    __syncthreads();             // gt(ch0) visible
    stage_v(vlds[1], c0 + 1);    // in flight across K-loop ch0
    f32x4 accA[4][2] = {};
    kloop(vlds[0], accA);
    __syncthreads();             // drains vlds[1] DMA; all waves done with gt + vlds[0]
    build_gt(d2l[1]);
    outstage(vlds[0], accA);
    __syncthreads();             // gt(ch1) + staged mix(ch0) visible
    copyout(vlds[0], c0);
    f32x4 accB[4][2] = {};
    kloop(vlds[1], accB);
    __syncthreads();             // all waves done with vlds[1]
    outstage(vlds[1], accB);
    __syncthreads();
    copyout(vlds[1], c0 + 1);
}

// ---------------- K6: out = x2b + srms(mm), wave-per-row, bf16x8 vectorized ----------------
__launch_bounds__(256)
__global__ void final_kernel(const u16* __restrict__ x2b, const u16* __restrict__ m,
                             float* __restrict__ out) {
    int row = blockIdx.x * 4 + (threadIdx.x >> 6);
    int lane = threadIdx.x & 63;
    const u16* mr = m + (size_t)row * DIM_ + lane * 8;
    const u16* xr = x2b + (size_t)row * DIM_ + lane * 8;
    u16 mv[8];
    *reinterpret_cast<uint4*>(mv) = *reinterpret_cast<const uint4*>(mr);
    float f[8];
    float ss = 0.0f;
    #pragma unroll
    for (int i = 0; i < 8; ++i) { f[i] = b2f(mv[i]); ss = fmaf(f[i], f[i], ss); }
    #pragma unroll
    for (int o = 32; o > 0; o >>= 1) ss += __shfl_xor(ss, o, 64);
    float inv = 1.0f / (sqrtf(ss) * 0.044194173824159216f + 1e-8f);
    u16 xv[8];
    *reinterpret_cast<uint4*>(xv) = *reinterpret_cast<const uint4*>(xr);
    float* orow = out + (size_t)row * DIM_ + lane * 8;
    float4 o0, o1;
    o0.x = b2f(xv[0]) + f[0] * inv; o0.y = b2f(xv[1]) + f[1] * inv;
    o0.z = b2f(xv[2]) + f[2] * inv; o0.w = b2f(xv[3]) + f[3] * inv;
    o1.x = b2f(xv[4]) + f[4] * inv; o1.y = b2f(xv[5]) + f[5] * inv;
    o1.z = b2f(xv[6]) + f[6] * inv; o1.w = b2f(xv[7]) + f[7] * inv;
    *reinterpret_cast<float4*>(orow) = o0;
    *reinterpret_cast<float4*>(orow + 4) = o1;
}

extern "C" void kernel_launch(void* const* d_in, const int* in_sizes, int n_in,
                              void* d_out, int out_size, void* d_ws, size_t ws_size,
                              hipStream_t stream) {
    const float* x     = (const float*)d_in[0];
    const float* u_w   = (const float*)d_in[1];
    const float* u_b   = (const float*)d_in[2];
    const float* v_w   = (const float*)d_in[3];
    const float* v_b   = (const float*)d_in[4];
    const float* o_w   = (const float*)d_in[5];
    const float* o_b   = (const float*)d_in[6];
    const float* pos_w = (const float*)d_in[7];
    const float* pos_b = (const float*)d_in[8];
    const float* rpe_lw = (const float*)d_in[9];
    const float* rpe_lb = (const float*)d_in[10];
    const float* rpe_ow = (const float*)d_in[11];
    const float* rpe_ob = (const float*)d_in[12];
    const float* l1_w  = (const float*)d_in[13];
    const float* l1_b  = (const float*)d_in[14];
    const float* l2_w  = (const float*)d_in[15];
    const float* l2_b  = (const float*)d_in[16];
    const float* l3_w  = (const float*)d_in[17];
    const float* l3_b  = (const float*)d_in[18];
    float* out = (float*)d_out;

    // -------- workspace layout (u16 units unless noted) --------
    u16* coefR  = (u16*)d_ws;                  //  7,077,888  (1536 x 4608 ring)
    u16* xb     = coefR + 7077888;             //  8,388,608
    u16* u      = xb + 8388608;                // 25,165,824
    u16* vT2    = u + 25165824;                // 25,165,824  [c][b*1024 + k], k=j'*32+i'
    u16* mixT   = vT2 + 25165824;              // 25,165,824  [c][r]
    u16* x2b    = mixT + 25165824;             //  8,388,608
    u16* uwT    = x2b + 8388608;               //    786,432
    u16* vwT    = uwT + 786432;
    u16* owT    = vwT + 786432;
    u16* gluT   = owT + 786432;                //  1,048,576 (l1T ++ l2T)
    u16* l3T    = gluT + 1048576;              //    524,288
    float* gluB = (float*)(l3T + 524288);      //      2,048 fp32
    u16* y      = (u16*)(gluB + 2048);         //    262,144  (4096 x 64)
    u16* owT2   = y + 262144;                  //     98,304  (1536 x 64)
    // overlays:
    u16* p      = u;                            // 16,777,216 (u dead after o-proj)
    u16* mm     = vT2;                          //  8,388,608 (vT2 dead after conv)

    const int M = B_ * NN;  // 16384

    // 1) fused prep: cvt + all transposes + bias concat + RPE hidden
    prep_kernel<<<7016, 256, 0, stream>>>(x, xb, u_w, uwT, v_w, vwT, o_w, owT,
                                          l1_w, l2_w, gluT, l3_w, l3T, rpe_ow, owT2,
                                          l1_b, l2_b, gluB, pos_w, pos_b, rpe_lw, rpe_lb, y);
    // 2) coefR = ring((rpe_ow^T @ y^T + ob) * decay)  [direct, bit-swap cols]
    mfma_gemm<6, 3><<<dim3(4096 / 128, D1_ / 128), 256, 0, stream>>>(owT2, y, rpe_ob, nullptr, coefR, nullptr, D1_, 4096, 64);
    // 3) vT2 = silu(v_w^T @ x^T) with position-permuted cols  [1536 x 16384 bf16]
    mfma_gemm<4, 1><<<dim3(M / 128, D1_ / 128), 256, 0, stream>>>(vwT, xb, v_b, nullptr, vT2, nullptr, D1_, M, DIM_);
    // 4) token mixing on matrix cores: mixT[c][r]  (2 channels per block, dbuf prefetch)
    conv_mfma_kernel<<<768, 512, 0, stream>>>(coefR, vT2, mixT);
    // 5) u = silu(x@u_w+b) * mix   [mult fused into epilogue; mix tile LDS-staged]
    mfma_gemm<7, 0><<<dim3(D1_ / 128, M / 128), 256, 0, stream>>>(xb, uwT, u_b, nullptr, u, mixT, M, D1_, DIM_);
    // 6) x2b = bf16(xb + u@o_w + b)   [residual read as bf16]
    mfma_gemm<1, 0><<<dim3(DIM_ / 128, M / 128), 256, 0, stream>>>(u, owT, o_b, xb, x2b, nullptr, M, DIM_, D1_);
    // 7) p = silu(x2b@l1+b1)*(x2b@l2+b2)   [GLU fused, column-interleaved staging]
    mfma_gemm<5, 2><<<dim3(2 * GLU_ / 128, M / 128), 256, 0, stream>>>(x2b, gluT, gluB, nullptr, p, nullptr, M, 2 * GLU_, DIM_);
    // 8) mm = bf16(p@l3 + b3)
    mfma_gemm<2, 0><<<dim3(DIM_ / 128, M / 128), 256, 0, stream>>>(p, l3T, l3_b, nullptr, mm, nullptr, M, DIM_, GLU_);
    // 9) out = x2b + srms(mm)
    final_kernel<<<M / 4, 256, 0, stream>>>(x2b, mm, out);
}